// Round 5
// baseline (203.502 us; speedup 1.0000x reference)
//
#include <hip/hip_runtime.h>
#include <hip/hip_bf16.h>
#include <stdint.h>

#define BROWS 4096
#define DDIM  1024
#define LSTR  72   // fp8 LDS row stride (bytes): 64 + 8 pad -> dword stride 18,
                   // b64 frag reads 2-way (free), b128 staging writes 4/bank (optimal)

typedef float f32x4 __attribute__((ext_vector_type(4)));
#define PSCALE 64.0f          // p pre-scale so typical p (~1e-3) lands in e4m3 normal range
#define INV_PSCALE 0.015625f

__device__ __forceinline__ int pack4_fp8(float a, float b, float c, float d) {
    int w = __builtin_amdgcn_cvt_pk_fp8_f32(a, b, 0, false);
    w = __builtin_amdgcn_cvt_pk_fp8_f32(c, d, w, true);
    return w;
}

// ---------------------------------------------------------------------------
// Kernel 1: prep — log(q)->fp8, (64*p)->fp8, e[row]=sum p log p,
//   kl_div[row]=mean p(log p - log q); zero CS/CL/EL; label bitmask via ballot.
// ---------------------------------------------------------------------------
__global__ __launch_bounds__(256) void prep_kernel(
    const float* __restrict__ q, const float* __restrict__ p,
    const float* __restrict__ L,
    int* __restrict__ lq8, int* __restrict__ p8,   // packed 4x fp8 per int
    uint64_t* __restrict__ Lb,
    float* __restrict__ e, float* __restrict__ kld,
    float* __restrict__ CS, float* __restrict__ CL, float* __restrict__ EL)
{
    const int row = blockIdx.x;
    const int t   = threadIdx.x;
    const int wv  = t >> 6, ln = t & 63;

    const float4* qv4 = (const float4*)(q + (size_t)row * DDIM);
    const float4* pv4 = (const float4*)(p + (size_t)row * DDIM);
    float4 qv = qv4[t];
    float4 pv = pv4[t];

    float lq0 = __logf(qv.x), lq1 = __logf(qv.y), lq2 = __logf(qv.z), lq3 = __logf(qv.w);
    float lp0 = __logf(pv.x), lp1 = __logf(pv.y), lp2 = __logf(pv.z), lp3 = __logf(pv.w);

    float esum = pv.x * lp0 + pv.y * lp1 + pv.z * lp2 + pv.w * lp3;
    float ksum = pv.x * (lp0 - lq0) + pv.y * (lp1 - lq1)
               + pv.z * (lp2 - lq2) + pv.w * (lp3 - lq3);

    lq8[row * 256 + t] = pack4_fp8(lq0, lq1, lq2, lq3);
    p8 [row * 256 + t] = pack4_fp8(pv.x * PSCALE, pv.y * PSCALE,
                                   pv.z * PSCALE, pv.w * PSCALE);

    const float* Lrow = L + (size_t)row * BROWS;
    #pragma unroll
    for (int c = 0; c < 16; c++) {
        float v = Lrow[c * 256 + t];
        unsigned long long m = __ballot(v != 0.0f);
        if (ln == 0) Lb[(size_t)row * 64 + c * 4 + wv] = m;
    }

    if (t == 0) { CS[row] = 0.f; CL[row] = 0.f; EL[row] = 0.f; }

    #pragma unroll
    for (int off = 32; off > 0; off >>= 1) {
        esum += __shfl_down(esum, off);
        ksum += __shfl_down(ksum, off);
    }
    __shared__ float se[4], sk[4];
    if (ln == 0) { se[wv] = esum; sk[wv] = ksum; }
    __syncthreads();
    if (t == 0) {
        e[row]   = se[0] + se[1] + se[2] + se[3];
        kld[row] = (sk[0] + sk[1] + sk[2] + sk[3]) * (1.0f / DDIM);
    }
}

// ---------------------------------------------------------------------------
// Kernel 2: cross = log_q @ p^T in fp8 e4m3 (non-scaled MFMA = bf16 rate,
//   half the staging bytes). Tile 256x256, 1024 threads (16 waves, each
//   64x64), K-chunk 64, 2-DEEP register prefetch (vmcnt(2) slack = 2 chunk
//   periods). Grid 16x16 = 1 block/CU. LDS stride 72 B: conflict-optimal.
// ---------------------------------------------------------------------------
__global__ __launch_bounds__(1024, 4) void gemm_epi_kernel(
    const uint8_t* __restrict__ A8,   // fp8 log_q [B,D]
    const uint8_t* __restrict__ B8,   // fp8 64*p  [B,D]
    const uint64_t* __restrict__ Lb,  // [B, B/64] bitmask
    const float*  __restrict__ e,     // [B]
    float* __restrict__ CS, float* __restrict__ CL, float* __restrict__ EL)
{
    __shared__ __align__(16) uint8_t As[256 * LSTR];  // 18 KB
    __shared__ __align__(16) uint8_t Bs[256 * LSTR];  // 18 KB

    const int t    = threadIdx.x;
    const int i0   = blockIdx.y * 256;
    const int j0   = blockIdx.x * 256;
    const int wave = t >> 6;
    const int lane = t & 63;
    const int q4   = lane >> 4;
    const int ln   = lane & 15;
    const int wrow = wave & 3;    // 4 i-subtiles of 64
    const int wcol = wave >> 2;   // 4 j-subtiles of 64

    f32x4 acc[4][4];
    #pragma unroll
    for (int a = 0; a < 4; a++)
        #pragma unroll
        for (int b = 0; b < 4; b++)
            acc[a][b] = (f32x4){0.f, 0.f, 0.f, 0.f};

    // staging: chunk = 256 rows x 64 B = 1024 x 16B units; 1 unit/thread
    const int srow = t >> 2;
    const int scol = (t & 3) * 16;
    const uint8_t* gA = A8 + (size_t)(i0 + srow) * DDIM + scol;
    const uint8_t* gB = B8 + (size_t)(j0 + srow) * DDIM + scol;
    const int loff = srow * LSTR + scol;

    int4 pfA[2], pfB[2];
    pfA[0] = *(const int4*)(gA);       pfB[0] = *(const int4*)(gB);
    pfA[1] = *(const int4*)(gA + 64);  pfB[1] = *(const int4*)(gB + 64);

    #pragma unroll 1
    for (int c = 0; c < DDIM / 64; ++c) {
        const int buf = c & 1;
        __syncthreads();                       // prior chunk's readers done
        *(int4*)(As + loff) = pfA[buf];
        *(int4*)(Bs + loff) = pfB[buf];
        __syncthreads();                       // chunk c visible

        if (c + 2 < DDIM / 64) {               // refill the slot just written
            pfA[buf] = *(const int4*)(gA + (c + 2) * 64);
            pfB[buf] = *(const int4*)(gB + (c + 2) * 64);
        }

        #pragma unroll
        for (int ks = 0; ks < 2; ks++) {
            long af[4], bfv[4];
            #pragma unroll
            for (int mi = 0; mi < 4; mi++)
                af[mi] = *(const long*)(As + (wrow * 64 + mi * 16 + ln) * LSTR
                                           + ks * 32 + q4 * 8);
            #pragma unroll
            for (int ni = 0; ni < 4; ni++)
                bfv[ni] = *(const long*)(Bs + (wcol * 64 + ni * 16 + ln) * LSTR
                                            + ks * 32 + q4 * 8);
            #pragma unroll
            for (int mi = 0; mi < 4; mi++)
                #pragma unroll
                for (int ni = 0; ni < 4; ni++)
                    acc[mi][ni] = __builtin_amdgcn_mfma_f32_16x16x32_fp8_fp8(
                        af[mi], bfv[ni], acc[mi][ni], 0, 0, 0);
        }
    }

    // ---- epilogue: C/D col = lane&15 (=j), row = quad*4+reg (=i); /PSCALE ----
    const int i_base = i0 + wrow * 64;
    const int j_base = j0 + wcol * 64;

    float e_j[4];
    #pragma unroll
    for (int ni = 0; ni < 4; ni++) e_j[ni] = e[j_base + ni * 16 + ln];

    #pragma unroll
    for (int mi = 0; mi < 4; mi++) {
        #pragma unroll
        for (int r = 0; r < 4; r++) {
            const int i = i_base + mi * 16 + q4 * 4 + r;
            const uint64_t m  = Lb[(size_t)i * 64 + (j_base >> 6)];
            const uint64_t ms = m >> ln;
            float cs = 0.f, cl = 0.f, el = 0.f;
            #pragma unroll
            for (int ni = 0; ni < 4; ni++) {
                float c = acc[mi][ni][r];
                cs += c;
                if ((ms >> (ni * 16)) & 1ull) { cl += c; el += e_j[ni]; }
            }
            #pragma unroll
            for (int s = 1; s < 16; s <<= 1) {
                cs += __shfl_xor(cs, s);
                cl += __shfl_xor(cl, s);
                el += __shfl_xor(el, s);
            }
            if (ln == 0) {
                atomicAdd(&CS[i], cs * INV_PSCALE);
                atomicAdd(&CL[i], cl * INV_PSCALE);
                atomicAdd(&EL[i], el);
            }
        }
    }
}

// ---------------------------------------------------------------------------
// Kernel 3: final — Etot = sum e; result = sum_i pos/neg
// ---------------------------------------------------------------------------
__global__ __launch_bounds__(1024) void final_kernel(
    const float* __restrict__ e, const float* __restrict__ kld,
    const float* __restrict__ CS, const float* __restrict__ CL,
    const float* __restrict__ EL, float* __restrict__ out)
{
    __shared__ float sred[16];
    __shared__ float sEtot;
    const int t = threadIdx.x;
    const int wv = t >> 6, ln = t & 63;

    float s = 0.f;
    for (int j = t; j < BROWS; j += 1024) s += e[j];
    #pragma unroll
    for (int off = 32; off > 0; off >>= 1) s += __shfl_down(s, off);
    if (ln == 0) sred[wv] = s;
    __syncthreads();
    if (t == 0) {
        float a = 0.f;
        #pragma unroll
        for (int k = 0; k < 16; k++) a += sred[k];
        sEtot = a;
    }
    __syncthreads();
    const float Etot = sEtot;
    const float invD = 1.0f / DDIM;

    float rs = 0.f;
    for (int i = t; i < BROWS; i += 1024) {
        float el = EL[i], cl = CL[i], cs = CS[i];
        float pos = kld[i] + (el - cl) * invD;
        float neg = (Etot - el - cs + cl) * invD;
        rs += pos / neg;
    }
    __syncthreads();
    #pragma unroll
    for (int off = 32; off > 0; off >>= 1) rs += __shfl_down(rs, off);
    if (ln == 0) sred[wv] = rs;
    __syncthreads();
    if (t == 0) {
        float a = 0.f;
        #pragma unroll
        for (int k = 0; k < 16; k++) a += sred[k];
        out[0] = a;
    }
}

// ---------------------------------------------------------------------------
extern "C" void kernel_launch(void* const* d_in, const int* in_sizes, int n_in,
                              void* d_out, int out_size, void* d_ws, size_t ws_size,
                              hipStream_t stream)
{
    const float* q = (const float*)d_in[0];
    const float* p = (const float*)d_in[1];
    const float* L = (const float*)d_in[2];
    float* out = (float*)d_out;

    char* ws = (char*)d_ws;
    int*  lq8 = (int*)ws;                                         // 4 MB
    int*  p8  = (int*)(ws + (size_t)BROWS * DDIM);                // 4 MB
    float* e  = (float*)(ws + (size_t)BROWS * DDIM * 2);          // 16 KB
    float* kld = e + BROWS;
    float* CS  = kld + BROWS;
    float* CL  = CS + BROWS;
    float* EL  = CL + BROWS;
    uint64_t* Lb = (uint64_t*)(EL + BROWS);                       // 2 MB

    prep_kernel<<<BROWS, 256, 0, stream>>>(q, p, L, lq8, p8, Lb, e, kld, CS, CL, EL);

    dim3 grid(BROWS / 256, BROWS / 256);
    gemm_epi_kernel<<<grid, 1024, 0, stream>>>(
        (const uint8_t*)lq8, (const uint8_t*)p8, Lb, e, CS, CL, EL);

    final_kernel<<<1, 1024, 0, stream>>>(e, kld, CS, CL, EL, out);
}